// Round 2
// baseline (594.433 us; speedup 1.0000x reference)
//
#include <hip/hip_runtime.h>

#define NR 4000
#define TS 60
#define DF 6
#define HD 64

__device__ __forceinline__ float sigf(float x) { return 1.0f / (1.0f + __expf(-x)); }
__device__ __forceinline__ float tanhfast(float x) { return 1.0f - 2.0f / (1.0f + __expf(2.0f * x)); }

__device__ __forceinline__ void matvec64b(const float* h,
                                          const float wr[64], const float wz[64], const float wn[64],
                                          float& ar, float& az, float& an) {
#pragma unroll
  for (int k4 = 0; k4 < 16; ++k4) {
    float4 hv = *(const float4*)(h + 4 * k4);
    ar = fmaf(wr[4 * k4 + 0], hv.x, ar);
    az = fmaf(wz[4 * k4 + 0], hv.x, az);
    an = fmaf(wn[4 * k4 + 0], hv.x, an);
    ar = fmaf(wr[4 * k4 + 1], hv.y, ar);
    az = fmaf(wz[4 * k4 + 1], hv.y, az);
    an = fmaf(wn[4 * k4 + 1], hv.y, an);
    ar = fmaf(wr[4 * k4 + 2], hv.z, ar);
    az = fmaf(wz[4 * k4 + 2], hv.z, az);
    an = fmaf(wn[4 * k4 + 2], hv.z, an);
    ar = fmaf(wr[4 * k4 + 3], hv.w, ar);
    az = fmaf(wz[4 * k4 + 3], hv.w, az);
    an = fmaf(wn[4 * k4 + 3], hv.w, an);
  }
}

// ---------------------------------------------------------------------------
// Kernel 1: fused 2-layer GRU. One block = one row, 3 waves:
//   wave 0 (A): layer-0 recurrence, Whh0 in registers
//   wave 1 (B): xp1 = h0_out @ Wih1^T, Wih1 in registers
//   wave 2 (C): layer-1 recurrence, Whh1 in registers
// Pipeline: A(t) -> B(t-1) -> C(t-2), one __syncthreads per phase.
// Epilogue (C): writes x_hidden row, a[i], c[i].
// ---------------------------------------------------------------------------
__global__ __launch_bounds__(192, 2) void gru_fused(
    const float* __restrict__ x,     // (4000, 360)
    const float* __restrict__ Wih0,  // (192,6)
    const float* __restrict__ Whh0,  // (192,64)
    const float* __restrict__ bih0, const float* __restrict__ bhh0,
    const float* __restrict__ Wih1,  // (192,64)
    const float* __restrict__ Whh1,  // (192,64)
    const float* __restrict__ bih1, const float* __restrict__ bhh1,
    const float* __restrict__ Wac,   // (128,)
    float* __restrict__ xh_out,      // (4000,64)
    float* __restrict__ a_out, float* __restrict__ c_out) {
  __shared__ float xlds[DF * TS];      // 360
  __shared__ float wi0lds[DF * 192];   // Wih0 transposed [f][j]
  __shared__ float h0buf[2][HD];
  __shared__ float xpbuf[2][3 * HD];
  __shared__ float h1buf[HD];

  const int r = blockIdx.x;
  const int tid = threadIdx.x;
  const int wid = tid >> 6;
  const int lane = tid & 63;

  // stage x row and Wih0 (transposed) into LDS
  for (int i = tid; i < DF * TS; i += 192) xlds[i] = x[r * (DF * TS) + i];
  for (int i = tid; i < DF * 192; i += 192) {
    int f = i / 192, j = i % 192;
    wi0lds[i] = Wih0[j * DF + f];
  }
  if (tid < HD) {
    h0buf[0][tid] = 0.f;
    h0buf[1][tid] = 0.f;
    h1buf[tid] = 0.f;
  }

  // per-wave weight matrix into registers (rows lane, lane+64, lane+128)
  const float* Wsel = (wid == 0) ? Whh0 : ((wid == 1) ? Wih1 : Whh1);
  float wr[64], wz[64], wn[64];
  {
    const float4* r0 = (const float4*)(Wsel + (size_t)lane * 64);
    const float4* r1 = (const float4*)(Wsel + (size_t)(lane + 64) * 64);
    const float4* r2 = (const float4*)(Wsel + (size_t)(lane + 128) * 64);
#pragma unroll
    for (int k4 = 0; k4 < 16; ++k4) {
      float4 a = r0[k4], b = r1[k4], c = r2[k4];
      wr[4 * k4 + 0] = a.x; wr[4 * k4 + 1] = a.y; wr[4 * k4 + 2] = a.z; wr[4 * k4 + 3] = a.w;
      wz[4 * k4 + 0] = b.x; wz[4 * k4 + 1] = b.y; wz[4 * k4 + 2] = b.z; wz[4 * k4 + 3] = b.w;
      wn[4 * k4 + 0] = c.x; wn[4 * k4 + 1] = c.y; wn[4 * k4 + 2] = c.z; wn[4 * k4 + 3] = c.w;
    }
  }

  // biases: b1* = input-side bias, b2* = hidden-side bias (per wave role)
  float b1r = 0.f, b1z = 0.f, b1n = 0.f, b2r = 0.f, b2z = 0.f, b2n = 0.f;
  if (wid == 0) {
    b1r = bih0[lane]; b1z = bih0[lane + 64]; b1n = bih0[lane + 128];
    b2r = bhh0[lane]; b2z = bhh0[lane + 64]; b2n = bhh0[lane + 128];
  } else if (wid == 1) {
    b1r = bih1[lane]; b1z = bih1[lane + 64]; b1n = bih1[lane + 128];
  } else {
    b2r = bhh1[lane]; b2z = bhh1[lane + 64]; b2n = bhh1[lane + 128];
  }

  float h0reg = 0.f, h1reg = 0.f;
  __syncthreads();

  for (int p = 0; p < TS + 2; ++p) {
    if (wid == 0) {
      if (p < TS) {
        const int t = p;
        float ar = b2r, az = b2z, an = b2n;  // bhh0
        matvec64b(h0buf[t & 1], wr, wz, wn, ar, az, an);
        float xr = b1r, xz = b1z, xn = b1n;  // bih0
#pragma unroll
        for (int f = 0; f < DF; ++f) {
          float xv = xlds[f * TS + t];
          xr = fmaf(wi0lds[f * 192 + lane], xv, xr);
          xz = fmaf(wi0lds[f * 192 + lane + 64], xv, xz);
          xn = fmaf(wi0lds[f * 192 + lane + 128], xv, xn);
        }
        float rg = sigf(xr + ar);
        float zg = sigf(xz + az);
        float ng = tanhfast(xn + rg * an);
        h0reg = fmaf(zg, h0reg - ng, ng);  // (1-z)n + z h
        h0buf[(t + 1) & 1][lane] = h0reg;
      }
    } else if (wid == 1) {
      if (p >= 1 && p < TS + 1) {
        const int u = p - 1;
        float ar = b1r, az = b1z, an = b1n;  // bih1
        matvec64b(h0buf[(u + 1) & 1], wr, wz, wn, ar, az, an);
        xpbuf[u & 1][lane] = ar;
        xpbuf[u & 1][lane + 64] = az;
        xpbuf[u & 1][lane + 128] = an;
      }
    } else {
      if (p >= 2) {
        const int v = p - 2;
        float ar = b2r, az = b2z, an = b2n;  // bhh1
        matvec64b(h1buf, wr, wz, wn, ar, az, an);
        float xr = xpbuf[v & 1][lane];
        float xz = xpbuf[v & 1][lane + 64];
        float xn = xpbuf[v & 1][lane + 128];
        float rg = sigf(xr + ar);
        float zg = sigf(xz + az);
        float ng = tanhfast(xn + rg * an);
        h1reg = fmaf(zg, h1reg - ng, ng);
        h1buf[lane] = h1reg;
      }
    }
    __syncthreads();
  }

  if (wid == 2) {
    xh_out[(size_t)r * HD + lane] = h1reg;
    float av = h1reg * Wac[lane];
    float cv = h1reg * Wac[64 + lane];
#pragma unroll
    for (int off = 32; off; off >>= 1) {
      av += __shfl_down(av, off);
      cv += __shfl_down(cv, off);
    }
    if (lane == 0) {
      a_out[r] = av;
      c_out[r] = cv;
    }
  }
}

// ---------------------------------------------------------------------------
// Kernel 2: masked graph attention + final FC, flash-style online softmax.
// 500 blocks x 256 threads; block = 8 rows i; j-chunks of 64 with x_hidden
// chunk staged in LDS. Each relation element read exactly once.
// Thread (il, tk): il = row-in-block (0..7), tk = 0..31; owns dims {2tk, 2tk+1}.
// ---------------------------------------------------------------------------
__global__ __launch_bounds__(256, 4) void attn_kernel(
    const float* __restrict__ rel,   // (4000,4000,3)
    const float* __restrict__ xh,    // (4000,64)
    const float* __restrict__ aArr, const float* __restrict__ cArr,
    const float* __restrict__ bSc,   // scalar
    const float* __restrict__ fcw,   // (128,)
    const float* __restrict__ fcb,   // (1,)
    float* __restrict__ pred) {
  __shared__ float xhl[64][64];  // 16KB
  __shared__ float pbuf[8][64];  // 2KB
  __shared__ float cl[64];

  const int tid = threadIdx.x;
  const int il = tid >> 5;
  const int tk = tid & 31;
  const int i = blockIdx.x * 8 + il;
  const float a_i = aArr[i];
  const float bb = bSc[0];

  float m = -3.0e38f, s = 0.f, acc0 = 0.f, acc1 = 0.f;

  for (int j0 = 0; j0 < NR; j0 += 64) {
    __syncthreads();  // previous chunk fully consumed before restage
    {
      const int jj = tid >> 2, seg = tid & 3;
      const int j = j0 + jj;
      float4* dst = (float4*)&xhl[jj][seg * 16];
      if (j < NR) {
        const float4* src = (const float4*)(xh + (size_t)j * 64 + seg * 16);
#pragma unroll
        for (int q = 0; q < 4; ++q) dst[q] = src[q];
      } else {
        float4 z = {0.f, 0.f, 0.f, 0.f};
#pragma unroll
        for (int q = 0; q < 4; ++q) dst[q] = z;
      }
      if (tid < 64) cl[tid] = (j0 + tid < NR) ? cArr[j0 + tid] : 0.f;
    }
    __syncthreads();

    // scores for this thread's two j's
    float vwa[2];
#pragma unroll
    for (int e = 0; e < 2; ++e) {
      const int jj = 2 * tk + e;
      const int j = j0 + jj;
      float v = -3.0e37f;
      if (j < NR) {
        const float* rp = rel + (long)i * (3L * NR) + (long)j * 3;
        const float msum = rp[0] + rp[1] + rp[2];
        float w = a_i + cl[jj] + bb;
        w = (w > 0.f) ? w : 0.01f * w;
        v = (msum == 0.f) ? -1.0e6f : msum * w;
      }
      vwa[e] = v;
    }
    float lm = fmaxf(vwa[0], vwa[1]);
#pragma unroll
    for (int off = 16; off; off >>= 1) lm = fmaxf(lm, __shfl_xor(lm, off, 32));
    const float mn = fmaxf(m, lm);
    const float f = __expf(m - mn);
    const float p0 = __expf(vwa[0] - mn);
    const float p1 = __expf(vwa[1] - mn);
    float ls = p0 + p1;
#pragma unroll
    for (int off = 16; off; off >>= 1) ls += __shfl_xor(ls, off, 32);
    s = s * f + ls;
    acc0 *= f;
    acc1 *= f;
    m = mn;
    pbuf[il][2 * tk] = p0;
    pbuf[il][2 * tk + 1] = p1;
    // pbuf row written & read by the same 32-lane group (wave-synchronous).

#pragma unroll 4
    for (int j4 = 0; j4 < 16; ++j4) {
      float4 pv = *(const float4*)&pbuf[il][4 * j4];
      float2 x0 = *(const float2*)&xhl[4 * j4 + 0][2 * tk];
      float2 x1 = *(const float2*)&xhl[4 * j4 + 1][2 * tk];
      float2 x2 = *(const float2*)&xhl[4 * j4 + 2][2 * tk];
      float2 x3 = *(const float2*)&xhl[4 * j4 + 3][2 * tk];
      acc0 = fmaf(pv.x, x0.x, acc0); acc1 = fmaf(pv.x, x0.y, acc1);
      acc0 = fmaf(pv.y, x1.x, acc0); acc1 = fmaf(pv.y, x1.y, acc1);
      acc0 = fmaf(pv.z, x2.x, acc0); acc1 = fmaf(pv.z, x2.y, acc1);
      acc0 = fmaf(pv.w, x3.x, acc0); acc1 = fmaf(pv.w, x3.y, acc1);
    }
  }

  const float inv = 1.0f / s;
  const float o0 = acc0 * inv, o1 = acc1 * inv;
  float2 xi = *(const float2*)(xh + (size_t)i * 64 + 2 * tk);
  float part = fcw[2 * tk] * xi.x + fcw[2 * tk + 1] * xi.y +
               fcw[64 + 2 * tk] * o0 + fcw[64 + 2 * tk + 1] * o1;
#pragma unroll
  for (int off = 16; off; off >>= 1) part += __shfl_xor(part, off, 32);
  if (tk == 0) pred[i] = part + fcb[0];
}

extern "C" void kernel_launch(void* const* d_in, const int* in_sizes, int n_in,
                              void* d_out, int out_size, void* d_ws, size_t ws_size,
                              hipStream_t stream) {
  const float* x    = (const float*)d_in[0];
  const float* rel  = (const float*)d_in[1];
  const float* Wih0 = (const float*)d_in[2];
  const float* Whh0 = (const float*)d_in[3];
  const float* bih0 = (const float*)d_in[4];
  const float* bhh0 = (const float*)d_in[5];
  const float* Wih1 = (const float*)d_in[6];
  const float* Whh1 = (const float*)d_in[7];
  const float* bih1 = (const float*)d_in[8];
  const float* bhh1 = (const float*)d_in[9];
  const float* Wac  = (const float*)d_in[10];
  const float* bSc  = (const float*)d_in[11];
  const float* fcw  = (const float*)d_in[12];
  const float* fcb  = (const float*)d_in[13];

  float* xh = (float*)d_ws;            // 4000*64 floats = 1,024,000 B
  float* aA = xh + (size_t)NR * HD;    // 4000
  float* cA = aA + NR;                 // 4000
  float* pred = (float*)d_out;

  gru_fused<<<NR, 192, 0, stream>>>(x, Wih0, Whh0, bih0, bhh0, Wih1, Whh1,
                                    bih1, bhh1, Wac, xh, aA, cA);
  attn_kernel<<<NR / 8, 256, 0, stream>>>(rel, xh, aA, cA, bSc, fcw, fcb, pred);
}